// Round 4
// baseline (811.145 us; speedup 1.0000x reference)
//
#include <hip/hip_runtime.h>

typedef __attribute__((ext_vector_type(8))) short short8;
typedef __attribute__((ext_vector_type(4))) float f32x4;
typedef unsigned short u16;

#define MFMA(a,b,c) __builtin_amdgcn_mfma_f32_16x16x32_bf16((a),(b),(c),0,0,0)

static __device__ __forceinline__ float us2f(u16 u){
  union { unsigned x; float f; } v; v.x = ((unsigned)u) << 16; return v.f;
}
static __device__ __forceinline__ u16 f2us(float f){
  union { float f; unsigned x; } v; v.f = f;
  unsigned r = v.x + 0x7FFFu + ((v.x >> 16) & 1u);
  return (u16)(r >> 16);
}
// XOR chunk swizzle for [R][C] u16 LDS tiles, 16B chunks. mask=7 for C>=64.
static __device__ __forceinline__ int swzN(int row, int col, int C){
  int ch = col >> 3;
  ch = (ch & ~7) | ((ch ^ row) & 7);
  return row*C + ch*8 + (col & 7);
}
// C=32 variant: 4 chunks/row, extra row>>2 term to spread 16 rows over banks
static __device__ __forceinline__ int swz32(int row, int col){
  int ch = col >> 3;
  ch = (ch ^ row ^ (row >> 2)) & 3;
  return row*32 + ch*8 + (col & 7);
}

// ---------------- K1: LN1 stats (mean, rstd) per pixel over channels -------
__global__ __launch_bounds__(256) void k_ln1_stats(const float* __restrict__ x,
    float* __restrict__ mean, float* __restrict__ rstd)
{
  const unsigned bh = blockIdx.x;          // b*256 + h
  const unsigned w  = threadIdx.x;
  const unsigned b = bh >> 8, h = bh & 255u;
  const float* px = x + (size_t)b*12582912u + (size_t)h*256u + w;
  float s = 0.f, q = 0.f;
  #pragma unroll 16
  for (int c = 0; c < 192; ++c) {
    float v = px[(size_t)c*65536u];
    s += v; q = fmaf(v, v, q);
  }
  float m = s * (1.f/192.f);
  float var = fmaf(-m, m, q * (1.f/192.f));
  unsigned p = bh*256u + w;
  mean[p] = m;
  rstd[p] = rsqrtf(fmaxf(var, 0.f) + 1e-5f);
}

// ---------------- K2: prep — transpose qkv_w/proj_w, weights -> bf16 -------
__global__ __launch_bounds__(256) void k_prep(
    const float* __restrict__ qkv_w, const float* __restrict__ proj_w,
    const float* __restrict__ fc1_w, const float* __restrict__ fc2_w,
    const float* __restrict__ fc3_w,
    u16* __restrict__ qkv_wT, u16* __restrict__ projT,
    u16* __restrict__ fc1c, u16* __restrict__ fc2c, u16* __restrict__ fc3c)
{
  const unsigned i = blockIdx.x*256u + threadIdx.x;          // < 589824
  if (i < 110592u) {                       // qkv_wT[r][t] = qkv_w[t][r]
    unsigned r = i / 192u, t = i - r*192u;
    qkv_wT[i] = f2us(qkv_w[(size_t)t*576u + r]);
  } else if (i < 147456u) {                // projT[c][t] = proj_w[t][c]
    unsigned j = i - 110592u, c = j / 192u, t = j - c*192u;
    projT[j] = f2us(proj_w[(size_t)t*192u + c]);
  } else if (i < 294912u) {
    unsigned j = i - 147456u; fc1c[j] = f2us(fc1_w[j]);
  } else if (i < 442368u) {
    unsigned j = i - 294912u; fc2c[j] = f2us(fc2_w[j]);
  } else {
    unsigned j = i - 442368u; fc3c[j] = f2us(fc3_w[j]);
  }
}

// ---------------- K3: per-window attention + fused LN2 -> z (B,H,W,C) ------
__global__ __launch_bounds__(768, 3) void k_attn(
    const float* __restrict__ x, const float* __restrict__ mean,
    const float* __restrict__ rstd,
    const float* __restrict__ g1, const float* __restrict__ b1,
    const u16* __restrict__ qkv_wT, const float* __restrict__ qkv_b,
    const float* __restrict__ bias_table,
    const u16* __restrict__ projT, const float* __restrict__ proj_b,
    const float* __restrict__ g2, const float* __restrict__ b2,
    u16* __restrict__ zbuf)
{
  extern __shared__ char smem[];
  u16*  ws_w  = (u16*)(smem);            // [64][192] swzN   (24576 B)
  u16*  ws_q  = (u16*)(smem + 24576);    // [6][64][32] swz32 (24576 B); later o
  u16*  ws_k  = (u16*)(smem + 49152);    // [6][64][32] swz32
  u16*  ws_vT = (u16*)(smem + 73728);    // [6][32][64] swzN
  u16*  ws_P  = (u16*)(smem + 98304);    // [6][64][64] swzN (49152 B)
  float* ws_y = (float*)(smem + 98304);  // [64][stride 193] f32 (49408 B, alias P)
  u16*  ws_o  = ws_q;                    // [64][192] swzN

  const int tid  = threadIdx.x;
  const int wave = tid >> 6;
  const int lane = tid & 63;
  const int l16  = lane & 15;
  const int lhi  = lane >> 4;
  const unsigned bw = blockIdx.x;

  // phase 0: gather scrambled window + apply LN1 -> ws_w (swizzled write)
  {
    const unsigned fbase = bw * 12288u;
    #pragma unroll 4
    for (int i = tid; i < 12288; i += 768) {
      unsigned f  = fbase + (unsigned)i;
      unsigned w_ = f & 255u;
      unsigned h2 = (f >> 8) & 7u;
      unsigned c2 = (f >> 11) & 7u;
      unsigned h1 = (f >> 14) & 31u;
      unsigned t19 = f >> 19;
      unsigned b_ = (t19 >= 24u) ? 1u : 0u;
      unsigned c1 = t19 - b_*24u;
      unsigned c  = c1*8u + c2;
      unsigned h  = h1*8u + h2;
      unsigned p  = (b_*256u + h)*256u + w_;
      size_t xi = ((size_t)(b_*192u + c)*256u + h)*256u + w_;
      float v = x[xi];
      v = (v - mean[p]) * rstd[p] * g1[c] + b1[c];
      int row = i / 192, col = i - row*192;
      ws_w[swzN(row, col, 192)] = f2us(v);
    }
  }
  __syncthreads();

  // phase 1: qkv = w @ qkv_wT + qkv_b ; scatter to q/k/vT. wave -> 48 cols.
  {
    f32x4 acc[4][3];
    #pragma unroll
    for (int mt = 0; mt < 4; ++mt)
      #pragma unroll
      for (int nt = 0; nt < 3; ++nt) acc[mt][nt] = (f32x4){0.f,0.f,0.f,0.f};
    const int jb = wave * 48;
    const int which = wave >> 2;           // 0 q, 1 k, 2 v (wave-uniform)
    #pragma unroll
    for (int kk = 0; kk < 6; ++kk) {
      const int kb = kk*32 + lhi*8;
      short8 a[4];
      #pragma unroll
      for (int mt = 0; mt < 4; ++mt)
        a[mt] = *(const short8*)(ws_w + swzN(mt*16 + l16, kb, 192));
      #pragma unroll
      for (int nt = 0; nt < 3; ++nt) {
        short8 bfr = *(const short8*)(qkv_wT + (size_t)(jb + nt*16 + l16)*192 + kb);
        #pragma unroll
        for (int mt = 0; mt < 4; ++mt)
          acc[mt][nt] = MFMA(a[mt], bfr, acc[mt][nt]);
      }
    }
    #pragma unroll
    for (int nt = 0; nt < 3; ++nt) {
      const int j = jb + nt*16 + l16;
      const int rj = j - which*192;
      const int head = rj >> 5;
      const int d = rj & 31;
      const float qb = qkv_b[j];
      #pragma unroll
      for (int mt = 0; mt < 4; ++mt)
        #pragma unroll
        for (int jr = 0; jr < 4; ++jr) {
          const int n = mt*16 + lhi*4 + jr;
          float v = acc[mt][nt][jr] + qb;
          if (which == 0)      ws_q[head*2048 + swz32(n, d)] = f2us(v * 0.17677669529663687f);
          else if (which == 1) ws_k[head*2048 + swz32(n, d)] = f2us(v);
          else                 ws_vT[head*2048 + swzN(d, n, 64)] = f2us(v);
        }
    }
  }
  __syncthreads();

  // phase 2: S = q k^T + bias ; softmax ; P. wave -> (head, half of rows).
  {
    const int head = wave >> 1, half = wave & 1;
    f32x4 sacc[2][4];
    #pragma unroll
    for (int ti = 0; ti < 2; ++ti)
      #pragma unroll
      for (int tc = 0; tc < 4; ++tc) sacc[ti][tc] = (f32x4){0.f,0.f,0.f,0.f};
    const int kb0 = lhi*8;
    short8 aq[2];
    #pragma unroll
    for (int ti = 0; ti < 2; ++ti)
      aq[ti] = *(const short8*)(ws_q + head*2048 + swz32((half*2 + ti)*16 + l16, kb0));
    #pragma unroll
    for (int tc = 0; tc < 4; ++tc) {
      short8 bk = *(const short8*)(ws_k + head*2048 + swz32(tc*16 + l16, kb0));
      #pragma unroll
      for (int ti = 0; ti < 2; ++ti)
        sacc[ti][tc] = MFMA(aq[ti], bk, sacc[ti][tc]);
    }
    #pragma unroll
    for (int ti = 0; ti < 2; ++ti)
      #pragma unroll
      for (int jr = 0; jr < 4; ++jr) {
        const int row = (half*2 + ti)*16 + lhi*4 + jr;
        const int yi = row >> 3, xi = row & 7;
        float m = -1e30f;
        #pragma unroll
        for (int tc = 0; tc < 4; ++tc) {
          const int col = tc*16 + l16;
          const int yj = col >> 3, xj = col & 7;
          const int idx = (yi - yj + 7)*15 + (xi - xj + 7);
          float v = sacc[ti][tc][jr] + bias_table[idx*6 + head];
          sacc[ti][tc][jr] = v;
          m = fmaxf(m, v);
        }
        m = fmaxf(m, __shfl_xor(m, 1));
        m = fmaxf(m, __shfl_xor(m, 2));
        m = fmaxf(m, __shfl_xor(m, 4));
        m = fmaxf(m, __shfl_xor(m, 8));
        float ssum = 0.f;
        #pragma unroll
        for (int tc = 0; tc < 4; ++tc) {
          float e = __expf(sacc[ti][tc][jr] - m);
          sacc[ti][tc][jr] = e;
          ssum += e;
        }
        ssum += __shfl_xor(ssum, 1);
        ssum += __shfl_xor(ssum, 2);
        ssum += __shfl_xor(ssum, 4);
        ssum += __shfl_xor(ssum, 8);
        const float inv = 1.0f / ssum;
        #pragma unroll
        for (int tc = 0; tc < 4; ++tc) {
          const int col = tc*16 + l16;
          ws_P[head*4096 + swzN(row, col, 64)] = f2us(sacc[ti][tc][jr] * inv);
        }
      }
  }
  __syncthreads();

  // phase 3: O = P @ V -> ws_o (aliases q). wave -> (head, half).
  {
    const int head = wave >> 1, half = wave & 1;
    f32x4 oacc[2][2];
    #pragma unroll
    for (int ti = 0; ti < 2; ++ti)
      #pragma unroll
      for (int td = 0; td < 2; ++td) oacc[ti][td] = (f32x4){0.f,0.f,0.f,0.f};
    #pragma unroll
    for (int kk = 0; kk < 2; ++kk) {
      const int kb = kk*32 + lhi*8;
      short8 ap[2];
      #pragma unroll
      for (int ti = 0; ti < 2; ++ti)
        ap[ti] = *(const short8*)(ws_P + head*4096 + swzN((half*2 + ti)*16 + l16, kb, 64));
      #pragma unroll
      for (int td = 0; td < 2; ++td) {
        short8 bv = *(const short8*)(ws_vT + head*2048 + swzN(td*16 + l16, kb, 64));
        #pragma unroll
        for (int ti = 0; ti < 2; ++ti)
          oacc[ti][td] = MFMA(ap[ti], bv, oacc[ti][td]);
      }
    }
    #pragma unroll
    for (int td = 0; td < 2; ++td)
      #pragma unroll
      for (int ti = 0; ti < 2; ++ti)
        #pragma unroll
        for (int jr = 0; jr < 4; ++jr) {
          const int n = (half*2 + ti)*16 + lhi*4 + jr;
          const int d = td*16 + l16;
          ws_o[swzN(n, head*32 + d, 192)] = f2us(oacc[ti][td][jr]);
        }
  }
  __syncthreads();

  // phase 4: proj + residual(w) -> ws_y f32 stride 193. wave -> 16 cols.
  {
    const int cb = wave * 16;
    f32x4 pacc[4];
    #pragma unroll
    for (int mt = 0; mt < 4; ++mt) pacc[mt] = (f32x4){0.f,0.f,0.f,0.f};
    #pragma unroll
    for (int kk = 0; kk < 6; ++kk) {
      const int kb = kk*32 + lhi*8;
      short8 bp = *(const short8*)(projT + (size_t)(cb + l16)*192 + kb);
      #pragma unroll
      for (int mt = 0; mt < 4; ++mt) {
        short8 a = *(const short8*)(ws_o + swzN(mt*16 + l16, kb, 192));
        pacc[mt] = MFMA(a, bp, pacc[mt]);
      }
    }
    const int cc = cb + l16;
    const float pb = proj_b[cc];
    #pragma unroll
    for (int mt = 0; mt < 4; ++mt)
      #pragma unroll
      for (int jr = 0; jr < 4; ++jr) {
        const int n = mt*16 + lhi*4 + jr;
        ws_y[n*193 + cc] = pacc[mt][jr] + pb + us2f(ws_w[swzN(n, cc, 192)]);
      }
  }
  __syncthreads();

  // phase 5: LN2 over channels of y, write z (B,H,W,C) bf16. 4 lanes/pixel.
  if (tid < 256) {
    const int pi = tid >> 2;
    const int part = tid & 3;
    const int c0 = part * 48;
    float vals[48];
    float s = 0.f, q = 0.f;
    #pragma unroll
    for (int c = 0; c < 48; ++c) {
      float v = ws_y[pi*193 + c0 + c];
      vals[c] = v; s += v; q = fmaf(v, v, q);
    }
    s += __shfl_xor(s, 1); s += __shfl_xor(s, 2);
    q += __shfl_xor(q, 1); q += __shfl_xor(q, 2);
    const float m = s * (1.f/192.f);
    const float var = fmaf(-m, m, q * (1.f/192.f));
    const float rs = rsqrtf(fmaxf(var, 0.f) + 1e-5f);
    const int b = (int)(bw >> 10);
    const int hh1 = (int)((bw >> 5) & 31u);
    const int ww1 = (int)(bw & 31u);
    const int h  = hh1*8 + (pi >> 3);
    const int w_ = ww1*8 + (pi & 7);
    size_t zo = ((size_t)((b*256 + h)*256 + w_))*192 + c0;
    #pragma unroll
    for (int c8 = 0; c8 < 6; ++c8) {
      short8 pk;
      #pragma unroll
      for (int j = 0; j < 8; ++j) {
        const int c = c8*8 + j;
        float z = (vals[c] - m)*rs*g2[c0+c] + b2[c0+c];
        pk[j] = (short)f2us(z);
      }
      *(short8*)(zbuf + zo + c8*8) = pk;
    }
  }
}

// ---------------- K4: gated FFN, 3 DF-chunks of 256, fc3 operand-swapped ---
__global__ __launch_bounds__(512, 4) void k_ffn(
    const u16* __restrict__ zbuf,
    const u16* __restrict__ fc1c, const float* __restrict__ fc1_b,
    const u16* __restrict__ fc2c, const float* __restrict__ fc2_b,
    const u16* __restrict__ fc3c, const float* __restrict__ fc3_b,
    float* __restrict__ out)
{
  extern __shared__ char smem[];
  u16* zt  = (u16*)smem;               // [64][192] swzN (24576 B)
  u16* htc = (u16*)(smem + 24576);     // [64][256] swzN (32768 B)

  const int tid = threadIdx.x;
  const int wave = tid >> 6, lane = tid & 63;
  const int l16 = lane & 15, lhi = lane >> 4;
  const size_t p0 = (size_t)blockIdx.x * 64u;

  // stage z tile (swizzled)
  for (int i8 = tid; i8 < 1536; i8 += 512) {
    int row = i8 / 24, ch = i8 - row*24;
    int chs = (ch & 24) | ((ch ^ row) & 7);
    *(short8*)(zt + row*192 + chs*8) =
        *(const short8*)(zbuf + (p0 + row)*192 + ch*8);
  }
  __syncthreads();

  f32x4 facc[3][2];
  #pragma unroll
  for (int tm = 0; tm < 3; ++tm)
    #pragma unroll
    for (int tn = 0; tn < 2; ++tn) facc[tm][tn] = (f32x4){0.f,0.f,0.f,0.f};
  const int wm = wave >> 1, wn = wave & 1;
  const int cb = wm*48, pbx = wn*32;
  const int jb = wave*32;

  #pragma unroll
  for (int rep = 0; rep < 3; ++rep) {
    // fc1/fc2 + gate for DF chunk [rep*256, rep*256+256) -> htc
    {
      f32x4 acc1[4][2], acc2[4][2];
      #pragma unroll
      for (int mt = 0; mt < 4; ++mt)
        #pragma unroll
        for (int nt = 0; nt < 2; ++nt) {
          acc1[mt][nt] = (f32x4){0.f,0.f,0.f,0.f};
          acc2[mt][nt] = (f32x4){0.f,0.f,0.f,0.f};
        }
      #pragma unroll
      for (int kk = 0; kk < 6; ++kk) {
        const int kb = kk*32 + lhi*8;
        short8 a[4];
        #pragma unroll
        for (int mt = 0; mt < 4; ++mt)
          a[mt] = *(const short8*)(zt + swzN(mt*16 + l16, kb, 192));
        #pragma unroll
        for (int nt = 0; nt < 2; ++nt) {
          const int oc = rep*256 + jb + nt*16 + l16;
          short8 bf1 = *(const short8*)(fc1c + (size_t)oc*192 + kb);
          short8 bf2 = *(const short8*)(fc2c + (size_t)oc*192 + kb);
          #pragma unroll
          for (int mt = 0; mt < 4; ++mt) {
            acc1[mt][nt] = MFMA(a[mt], bf1, acc1[mt][nt]);
            acc2[mt][nt] = MFMA(a[mt], bf2, acc2[mt][nt]);
          }
        }
      }
      #pragma unroll
      for (int nt = 0; nt < 2; ++nt) {
        const int ocl = jb + nt*16 + l16;          // local col in chunk
        const int oc  = rep*256 + ocl;
        const float bb1 = fc1_b[oc];
        const float bb2 = fc2_b[oc];
        #pragma unroll
        for (int mt = 0; mt < 4; ++mt)
          #pragma unroll
          for (int jr = 0; jr < 4; ++jr) {
            const int row = mt*16 + lhi*4 + jr;
            float h1 = acc1[mt][nt][jr] + bb1;
            h1 = 1.f / (1.f + __expf(-h1));
            const float g = h1 * (acc2[mt][nt][jr] + bb2);
            htc[swzN(row, ocl, 256)] = f2us(g);
          }
      }
    }
    __syncthreads();

    // fc3 partial: facc += W3[:, chunk] (x) htc^T.  A=weights, B=htc (swapped)
    #pragma unroll
    for (int kk = 0; kk < 8; ++kk) {
      const int kb = kk*32 + lhi*8;
      short8 bfr[2];
      #pragma unroll
      for (int tn = 0; tn < 2; ++tn)
        bfr[tn] = *(const short8*)(htc + swzN(pbx + tn*16 + l16, kb, 256));
      #pragma unroll
      for (int tm = 0; tm < 3; ++tm) {
        short8 aw = *(const short8*)(fc3c + (size_t)(cb + tm*16 + l16)*768
                                     + rep*256 + kb);
        #pragma unroll
        for (int tn = 0; tn < 2; ++tn)
          facc[tm][tn] = MFMA(aw, bfr[tn], facc[tm][tn]);
      }
    }
    __syncthreads();   // before next rep overwrites htc
  }

  // epilogue: + fc3_b + residual(z), direct coalesced store (B,C,H,W) f32
  const int b  = (int)(p0 >> 16);
  const int h  = (int)((p0 >> 8) & 255u);
  const int w0 = (int)(p0 & 255u);
  #pragma unroll
  for (int tm = 0; tm < 3; ++tm)
    #pragma unroll
    for (int jr = 0; jr < 4; ++jr) {
      const int qc = cb + tm*16 + lhi*4 + jr;
      const float fb = fc3_b[qc];
      #pragma unroll
      for (int tn = 0; tn < 2; ++tn) {
        const int pix = pbx + tn*16 + l16;
        const float v = facc[tm][tn][jr] + fb + us2f(zt[swzN(pix, qc, 192)]);
        out[((size_t)(b*192 + qc)*256 + h)*256 + w0 + pix] = v;
      }
    }
}

extern "C" void kernel_launch(void* const* d_in, const int* in_sizes, int n_in,
                              void* d_out, int out_size, void* d_ws, size_t ws_size,
                              hipStream_t stream)
{
  const float* x       = (const float*)d_in[0];
  const float* ln1_g   = (const float*)d_in[1];
  const float* ln1_b   = (const float*)d_in[2];
  const float* qkv_w   = (const float*)d_in[3];
  const float* qkv_b   = (const float*)d_in[4];
  const float* bias_tb = (const float*)d_in[5];
  const float* proj_w  = (const float*)d_in[6];
  const float* proj_b  = (const float*)d_in[7];
  const float* ln2_g   = (const float*)d_in[8];
  const float* ln2_b   = (const float*)d_in[9];
  const float* fc1_w   = (const float*)d_in[10];
  const float* fc1_b   = (const float*)d_in[11];
  const float* fc2_w   = (const float*)d_in[12];
  const float* fc2_b   = (const float*)d_in[13];
  const float* fc3_w   = (const float*)d_in[14];
  const float* fc3_b   = (const float*)d_in[15];
  float* outp = (float*)d_out;

  char* ws = (char*)d_ws;
  float* meanp  = (float*)(ws);                // 524288 B
  float* rstdp  = (float*)(ws + 524288);       // 524288 B
  u16*   qkv_wT = (u16*)(ws + 1048576);        // 221184 B
  u16*   projT  = (u16*)(ws + 1269760);        // 73728 B
  u16*   fc1c   = (u16*)(ws + 1343488);        // 294912 B
  u16*   fc2c   = (u16*)(ws + 1638400);        // 294912 B
  u16*   fc3c   = (u16*)(ws + 1933312);        // 294912 B
  u16*   zbuf   = (u16*)(ws + 2228224);        // 50331648 B (total ~52.6 MB)

  hipFuncSetAttribute((const void*)k_attn, hipFuncAttributeMaxDynamicSharedMemorySize, 147712);
  hipFuncSetAttribute((const void*)k_ffn,  hipFuncAttributeMaxDynamicSharedMemorySize, 57344);

  k_ln1_stats<<<512, 256, 0, stream>>>(x, meanp, rstdp);
  k_prep<<<2304, 256, 0, stream>>>(qkv_w, proj_w, fc1_w, fc2_w, fc3_w,
                                   qkv_wT, projT, fc1c, fc2c, fc3c);
  k_attn<<<2048, 768, 147712, stream>>>(x, meanp, rstdp, ln1_g, ln1_b,
                                        qkv_wT, qkv_b, bias_tb, projT, proj_b,
                                        ln2_g, ln2_b, zbuf);
  k_ffn<<<2048, 512, 57344, stream>>>(zbuf, fc1c, fc1_b, fc2c, fc2_b,
                                      fc3c, fc3_b, outp);
}

// Round 5
// 799.889 us; speedup vs baseline: 1.0141x; 1.0141x over previous
//
#include <hip/hip_runtime.h>

typedef __attribute__((ext_vector_type(8))) short short8;
typedef __attribute__((ext_vector_type(4))) float f32x4;
typedef unsigned short u16;

#define MFMA(a,b,c) __builtin_amdgcn_mfma_f32_16x16x32_bf16((a),(b),(c),0,0,0)

static __device__ __forceinline__ float us2f(u16 u){
  union { unsigned x; float f; } v; v.x = ((unsigned)u) << 16; return v.f;
}
static __device__ __forceinline__ u16 f2us(float f){
  union { float f; unsigned x; } v; v.f = f;
  unsigned r = v.x + 0x7FFFu + ((v.x >> 16) & 1u);
  return (u16)(r >> 16);
}
// XOR chunk swizzle for [R][C] u16 LDS tiles, 16B chunks. mask=7 for C>=64.
static __device__ __forceinline__ int swzN(int row, int col, int C){
  int ch = col >> 3;
  ch = (ch & ~7) | ((ch ^ row) & 7);
  return row*C + ch*8 + (col & 7);
}
// C=32 variant: 4 chunks/row, extra row>>2 term to spread 16 rows over banks
static __device__ __forceinline__ int swz32(int row, int col){
  int ch = col >> 3;
  ch = (ch ^ row ^ (row >> 2)) & 3;
  return row*32 + ch*8 + (col & 7);
}

// ---------------- K1: LN1 stats (mean, rstd) per pixel over channels -------
__global__ __launch_bounds__(256) void k_ln1_stats(const float* __restrict__ x,
    float* __restrict__ mean, float* __restrict__ rstd)
{
  const unsigned bh = blockIdx.x;          // b*256 + h
  const unsigned w  = threadIdx.x;
  const unsigned b = bh >> 8, h = bh & 255u;
  const float* px = x + (size_t)b*12582912u + (size_t)h*256u + w;
  float s = 0.f, q = 0.f;
  #pragma unroll 16
  for (int c = 0; c < 192; ++c) {
    float v = px[(size_t)c*65536u];
    s += v; q = fmaf(v, v, q);
  }
  float m = s * (1.f/192.f);
  float var = fmaf(-m, m, q * (1.f/192.f));
  unsigned p = bh*256u + w;
  mean[p] = m;
  rstd[p] = rsqrtf(fmaxf(var, 0.f) + 1e-5f);
}

// ---------------- K2: prep — transpose qkv_w/proj_w, weights -> bf16 -------
__global__ __launch_bounds__(256) void k_prep(
    const float* __restrict__ qkv_w, const float* __restrict__ proj_w,
    const float* __restrict__ fc1_w, const float* __restrict__ fc2_w,
    const float* __restrict__ fc3_w,
    u16* __restrict__ qkv_wT, u16* __restrict__ projT,
    u16* __restrict__ fc1c, u16* __restrict__ fc2c, u16* __restrict__ fc3c)
{
  const unsigned i = blockIdx.x*256u + threadIdx.x;          // < 589824
  if (i < 110592u) {                       // qkv_wT[r][t] = qkv_w[t][r]
    unsigned r = i / 192u, t = i - r*192u;
    qkv_wT[i] = f2us(qkv_w[(size_t)t*576u + r]);
  } else if (i < 147456u) {                // projT[c][t] = proj_w[t][c]
    unsigned j = i - 110592u, c = j / 192u, t = j - c*192u;
    projT[j] = f2us(proj_w[(size_t)t*192u + c]);
  } else if (i < 294912u) {
    unsigned j = i - 147456u; fc1c[j] = f2us(fc1_w[j]);
  } else if (i < 442368u) {
    unsigned j = i - 294912u; fc2c[j] = f2us(fc2_w[j]);
  } else {
    unsigned j = i - 442368u; fc3c[j] = f2us(fc3_w[j]);
  }
}

// ---------------- K3: per-window attention + fused LN2 -> z (B,H,W,C) ------
__global__ __launch_bounds__(768, 3) void k_attn(
    const float* __restrict__ x, const float* __restrict__ mean,
    const float* __restrict__ rstd,
    const float* __restrict__ g1, const float* __restrict__ b1,
    const u16* __restrict__ qkv_wT, const float* __restrict__ qkv_b,
    const float* __restrict__ bias_table,
    const u16* __restrict__ projT, const float* __restrict__ proj_b,
    const float* __restrict__ g2, const float* __restrict__ b2,
    u16* __restrict__ zbuf)
{
  extern __shared__ char smem[];
  u16*  ws_w  = (u16*)(smem);            // [64][192] swzN   (24576 B)
  u16*  ws_q  = (u16*)(smem + 24576);    // [6][64][32] swz32 (24576 B); later o
  u16*  ws_k  = (u16*)(smem + 49152);    // [6][64][32] swz32
  u16*  ws_vT = (u16*)(smem + 73728);    // [6][32][64] swzN
  u16*  ws_P  = (u16*)(smem + 98304);    // [6][64][64] swzN (49152 B)
  float* ws_y = (float*)(smem + 98304);  // [64][stride 193] f32 (49408 B, alias P)
  u16*  ws_o  = ws_q;                    // [64][192] swzN

  const int tid  = threadIdx.x;
  const int wave = tid >> 6;
  const int lane = tid & 63;
  const int l16  = lane & 15;
  const int lhi  = lane >> 4;
  const unsigned bw = blockIdx.x;

  // phase 0: gather scrambled window + apply LN1 -> ws_w (swizzled write)
  {
    const unsigned fbase = bw * 12288u;
    #pragma unroll 4
    for (int i = tid; i < 12288; i += 768) {
      unsigned f  = fbase + (unsigned)i;
      unsigned w_ = f & 255u;
      unsigned h2 = (f >> 8) & 7u;
      unsigned c2 = (f >> 11) & 7u;
      unsigned h1 = (f >> 14) & 31u;
      unsigned t19 = f >> 19;
      unsigned b_ = (t19 >= 24u) ? 1u : 0u;
      unsigned c1 = t19 - b_*24u;
      unsigned c  = c1*8u + c2;
      unsigned h  = h1*8u + h2;
      unsigned p  = (b_*256u + h)*256u + w_;
      size_t xi = ((size_t)(b_*192u + c)*256u + h)*256u + w_;
      float v = x[xi];
      v = (v - mean[p]) * rstd[p] * g1[c] + b1[c];
      int row = i / 192, col = i - row*192;
      ws_w[swzN(row, col, 192)] = f2us(v);
    }
  }
  __syncthreads();

  // phase 1: qkv = w @ qkv_wT + qkv_b ; scatter to q/k/vT. wave -> 48 cols.
  {
    f32x4 acc[4][3];
    #pragma unroll
    for (int mt = 0; mt < 4; ++mt)
      #pragma unroll
      for (int nt = 0; nt < 3; ++nt) acc[mt][nt] = (f32x4){0.f,0.f,0.f,0.f};
    const int jb = wave * 48;
    const int which = wave >> 2;           // 0 q, 1 k, 2 v (wave-uniform)
    #pragma unroll
    for (int kk = 0; kk < 6; ++kk) {
      const int kb = kk*32 + lhi*8;
      short8 a[4];
      #pragma unroll
      for (int mt = 0; mt < 4; ++mt)
        a[mt] = *(const short8*)(ws_w + swzN(mt*16 + l16, kb, 192));
      #pragma unroll
      for (int nt = 0; nt < 3; ++nt) {
        short8 bfr = *(const short8*)(qkv_wT + (size_t)(jb + nt*16 + l16)*192 + kb);
        #pragma unroll
        for (int mt = 0; mt < 4; ++mt)
          acc[mt][nt] = MFMA(a[mt], bfr, acc[mt][nt]);
      }
    }
    #pragma unroll
    for (int nt = 0; nt < 3; ++nt) {
      const int j = jb + nt*16 + l16;
      const int rj = j - which*192;
      const int head = rj >> 5;
      const int d = rj & 31;
      const float qb = qkv_b[j];
      #pragma unroll
      for (int mt = 0; mt < 4; ++mt)
        #pragma unroll
        for (int jr = 0; jr < 4; ++jr) {
          const int n = mt*16 + lhi*4 + jr;
          float v = acc[mt][nt][jr] + qb;
          if (which == 0)      ws_q[head*2048 + swz32(n, d)] = f2us(v * 0.17677669529663687f);
          else if (which == 1) ws_k[head*2048 + swz32(n, d)] = f2us(v);
          else                 ws_vT[head*2048 + swzN(d, n, 64)] = f2us(v);
        }
    }
  }
  __syncthreads();

  // phase 2: S = q k^T + bias ; softmax ; P. wave -> (head, half of rows).
  {
    const int head = wave >> 1, half = wave & 1;
    f32x4 sacc[2][4];
    #pragma unroll
    for (int ti = 0; ti < 2; ++ti)
      #pragma unroll
      for (int tc = 0; tc < 4; ++tc) sacc[ti][tc] = (f32x4){0.f,0.f,0.f,0.f};
    const int kb0 = lhi*8;
    short8 aq[2];
    #pragma unroll
    for (int ti = 0; ti < 2; ++ti)
      aq[ti] = *(const short8*)(ws_q + head*2048 + swz32((half*2 + ti)*16 + l16, kb0));
    #pragma unroll
    for (int tc = 0; tc < 4; ++tc) {
      short8 bk = *(const short8*)(ws_k + head*2048 + swz32(tc*16 + l16, kb0));
      #pragma unroll
      for (int ti = 0; ti < 2; ++ti)
        sacc[ti][tc] = MFMA(aq[ti], bk, sacc[ti][tc]);
    }
    #pragma unroll
    for (int ti = 0; ti < 2; ++ti)
      #pragma unroll
      for (int jr = 0; jr < 4; ++jr) {
        const int row = (half*2 + ti)*16 + lhi*4 + jr;
        const int yi = row >> 3, xi = row & 7;
        float m = -1e30f;
        #pragma unroll
        for (int tc = 0; tc < 4; ++tc) {
          const int col = tc*16 + l16;
          const int yj = col >> 3, xj = col & 7;
          const int idx = (yi - yj + 7)*15 + (xi - xj + 7);
          float v = sacc[ti][tc][jr] + bias_table[idx*6 + head];
          sacc[ti][tc][jr] = v;
          m = fmaxf(m, v);
        }
        m = fmaxf(m, __shfl_xor(m, 1));
        m = fmaxf(m, __shfl_xor(m, 2));
        m = fmaxf(m, __shfl_xor(m, 4));
        m = fmaxf(m, __shfl_xor(m, 8));
        float ssum = 0.f;
        #pragma unroll
        for (int tc = 0; tc < 4; ++tc) {
          float e = __expf(sacc[ti][tc][jr] - m);
          sacc[ti][tc][jr] = e;
          ssum += e;
        }
        ssum += __shfl_xor(ssum, 1);
        ssum += __shfl_xor(ssum, 2);
        ssum += __shfl_xor(ssum, 4);
        ssum += __shfl_xor(ssum, 8);
        const float inv = 1.0f / ssum;
        #pragma unroll
        for (int tc = 0; tc < 4; ++tc) {
          const int col = tc*16 + l16;
          ws_P[head*4096 + swzN(row, col, 64)] = f2us(sacc[ti][tc][jr] * inv);
        }
      }
  }
  __syncthreads();

  // phase 3: O = P @ V -> ws_o (aliases q). wave -> (head, half).
  {
    const int head = wave >> 1, half = wave & 1;
    f32x4 oacc[2][2];
    #pragma unroll
    for (int ti = 0; ti < 2; ++ti)
      #pragma unroll
      for (int td = 0; td < 2; ++td) oacc[ti][td] = (f32x4){0.f,0.f,0.f,0.f};
    #pragma unroll
    for (int kk = 0; kk < 2; ++kk) {
      const int kb = kk*32 + lhi*8;
      short8 ap[2];
      #pragma unroll
      for (int ti = 0; ti < 2; ++ti)
        ap[ti] = *(const short8*)(ws_P + head*4096 + swzN((half*2 + ti)*16 + l16, kb, 64));
      #pragma unroll
      for (int td = 0; td < 2; ++td) {
        short8 bv = *(const short8*)(ws_vT + head*2048 + swzN(td*16 + l16, kb, 64));
        #pragma unroll
        for (int ti = 0; ti < 2; ++ti)
          oacc[ti][td] = MFMA(ap[ti], bv, oacc[ti][td]);
      }
    }
    #pragma unroll
    for (int td = 0; td < 2; ++td)
      #pragma unroll
      for (int ti = 0; ti < 2; ++ti)
        #pragma unroll
        for (int jr = 0; jr < 4; ++jr) {
          const int n = (half*2 + ti)*16 + lhi*4 + jr;
          const int d = td*16 + l16;
          ws_o[swzN(n, head*32 + d, 192)] = f2us(oacc[ti][td][jr]);
        }
  }
  __syncthreads();

  // phase 4: proj + residual(w) -> ws_y f32 stride 193. wave -> 16 cols.
  {
    const int cb = wave * 16;
    f32x4 pacc[4];
    #pragma unroll
    for (int mt = 0; mt < 4; ++mt) pacc[mt] = (f32x4){0.f,0.f,0.f,0.f};
    #pragma unroll
    for (int kk = 0; kk < 6; ++kk) {
      const int kb = kk*32 + lhi*8;
      short8 bp = *(const short8*)(projT + (size_t)(cb + l16)*192 + kb);
      #pragma unroll
      for (int mt = 0; mt < 4; ++mt) {
        short8 a = *(const short8*)(ws_o + swzN(mt*16 + l16, kb, 192));
        pacc[mt] = MFMA(a, bp, pacc[mt]);
      }
    }
    const int cc = cb + l16;
    const float pb = proj_b[cc];
    #pragma unroll
    for (int mt = 0; mt < 4; ++mt)
      #pragma unroll
      for (int jr = 0; jr < 4; ++jr) {
        const int n = mt*16 + lhi*4 + jr;
        ws_y[n*193 + cc] = pacc[mt][jr] + pb + us2f(ws_w[swzN(n, cc, 192)]);
      }
  }
  __syncthreads();

  // phase 5: LN2 over channels of y, write z (B,H,W,C) bf16. 8 lanes/pixel.
  if (tid < 512) {
    const int pi = tid >> 3;       // pixel 0..63
    const int part = tid & 7;
    const int c0 = part * 24;
    float vals[24];
    float s = 0.f, q = 0.f;
    #pragma unroll
    for (int c = 0; c < 24; ++c) {
      float v = ws_y[pi*193 + c0 + c];
      vals[c] = v; s += v; q = fmaf(v, v, q);
    }
    s += __shfl_xor(s, 1); s += __shfl_xor(s, 2); s += __shfl_xor(s, 4);
    q += __shfl_xor(q, 1); q += __shfl_xor(q, 2); q += __shfl_xor(q, 4);
    const float m = s * (1.f/192.f);
    const float var = fmaf(-m, m, q * (1.f/192.f));
    const float rs = rsqrtf(fmaxf(var, 0.f) + 1e-5f);
    const int b = (int)(bw >> 10);
    const int hh1 = (int)((bw >> 5) & 31u);
    const int ww1 = (int)(bw & 31u);
    const int h  = hh1*8 + (pi >> 3);
    const int w_ = ww1*8 + (pi & 7);
    size_t zo = ((size_t)((b*256 + h)*256 + w_))*192 + c0;
    #pragma unroll
    for (int c8 = 0; c8 < 3; ++c8) {
      short8 pk;
      #pragma unroll
      for (int j = 0; j < 8; ++j) {
        const int c = c8*8 + j;
        float z = (vals[c] - m)*rs*g2[c0+c] + b2[c0+c];
        pk[j] = (short)f2us(z);
      }
      *(short8*)(zbuf + zo + c8*8) = pk;
    }
  }
}

// ------- K4: gated FFN, 6 DF-chunks of 128, row-split waves, no spills -----
// 8 waves = 4 DF-groups (wdf) x 2 row-groups (wrow) for fc1/fc2;
// re-mapped to 4 qc-groups (wm) x 2 pixel-halves (wn) for fc3.
__global__ __launch_bounds__(512, 4) void k_ffn(
    const u16* __restrict__ zbuf,
    const u16* __restrict__ fc1c, const float* __restrict__ fc1_b,
    const u16* __restrict__ fc2c, const float* __restrict__ fc2_b,
    const u16* __restrict__ fc3c, const float* __restrict__ fc3_b,
    float* __restrict__ out)
{
  extern __shared__ char smem[];
  u16* zt  = (u16*)smem;               // [64][192] swzN (24576 B)
  u16* htc = (u16*)(smem + 24576);     // [64][128] swzN (16384 B)

  const int tid = threadIdx.x;
  const int wave = tid >> 6, lane = tid & 63;
  const int l16 = lane & 15, lhi = lane >> 4;
  const size_t p0 = (size_t)blockIdx.x * 64u;

  // stage z tile (swizzled)
  for (int i8 = tid; i8 < 1536; i8 += 512) {
    int row = i8 / 24, ch = i8 - row*24;
    int chs = (ch & 24) | ((ch ^ row) & 7);
    *(short8*)(zt + row*192 + chs*8) =
        *(const short8*)(zbuf + (p0 + row)*192 + ch*8);
  }
  __syncthreads();

  f32x4 facc[3][2];
  #pragma unroll
  for (int tm = 0; tm < 3; ++tm)
    #pragma unroll
    for (int tn = 0; tn < 2; ++tn) facc[tm][tn] = (f32x4){0.f,0.f,0.f,0.f};
  const int wm = wave >> 1, wn = wave & 1;      // fc3 wave map
  const int cb = wm*48, pbx = wn*32;
  const int wdf = wave & 3, wrow = wave >> 2;   // fc1/fc2 wave map

  for (int rep = 0; rep < 6; ++rep) {
    // fc1/fc2 + gate for DF chunk [rep*128, rep*128+128) -> htc
    {
      f32x4 acc1[2][2], acc2[2][2];
      #pragma unroll
      for (int mt = 0; mt < 2; ++mt)
        #pragma unroll
        for (int nt = 0; nt < 2; ++nt) {
          acc1[mt][nt] = (f32x4){0.f,0.f,0.f,0.f};
          acc2[mt][nt] = (f32x4){0.f,0.f,0.f,0.f};
        }
      #pragma unroll
      for (int kk = 0; kk < 6; ++kk) {
        const int kb = kk*32 + lhi*8;
        short8 a[2];
        #pragma unroll
        for (int mt = 0; mt < 2; ++mt)
          a[mt] = *(const short8*)(zt + swzN(wrow*32 + mt*16 + l16, kb, 192));
        #pragma unroll
        for (int nt = 0; nt < 2; ++nt) {
          const int oc = rep*128 + wdf*32 + nt*16 + l16;
          short8 bf1 = *(const short8*)(fc1c + (size_t)oc*192 + kb);
          short8 bf2 = *(const short8*)(fc2c + (size_t)oc*192 + kb);
          #pragma unroll
          for (int mt = 0; mt < 2; ++mt) {
            acc1[mt][nt] = MFMA(a[mt], bf1, acc1[mt][nt]);
            acc2[mt][nt] = MFMA(a[mt], bf2, acc2[mt][nt]);
          }
        }
      }
      #pragma unroll
      for (int nt = 0; nt < 2; ++nt) {
        const int ocl = wdf*32 + nt*16 + l16;      // local col in chunk
        const int oc  = rep*128 + ocl;
        const float bb1 = fc1_b[oc];
        const float bb2 = fc2_b[oc];
        #pragma unroll
        for (int mt = 0; mt < 2; ++mt)
          #pragma unroll
          for (int jr = 0; jr < 4; ++jr) {
            const int row = wrow*32 + mt*16 + lhi*4 + jr;
            float h1 = acc1[mt][nt][jr] + bb1;
            h1 = 1.f / (1.f + __expf(-h1));
            const float g = h1 * (acc2[mt][nt][jr] + bb2);
            htc[swzN(row, ocl, 128)] = f2us(g);
          }
      }
    }
    __syncthreads();

    // fc3 partial: facc += W3[:, chunk] (x) htc^T.  A=weights, B=htc (swapped)
    #pragma unroll
    for (int kk = 0; kk < 4; ++kk) {
      const int kb = kk*32 + lhi*8;
      short8 bfr[2];
      #pragma unroll
      for (int tn = 0; tn < 2; ++tn)
        bfr[tn] = *(const short8*)(htc + swzN(pbx + tn*16 + l16, kb, 128));
      #pragma unroll
      for (int tm = 0; tm < 3; ++tm) {
        short8 aw = *(const short8*)(fc3c + (size_t)(cb + tm*16 + l16)*768
                                     + rep*128 + kb);
        #pragma unroll
        for (int tn = 0; tn < 2; ++tn)
          facc[tm][tn] = MFMA(aw, bfr[tn], facc[tm][tn]);
      }
    }
    __syncthreads();   // before next rep overwrites htc
  }

  // epilogue: + fc3_b + residual(z), direct coalesced store (B,C,H,W) f32
  const int b  = (int)(p0 >> 16);
  const int h  = (int)((p0 >> 8) & 255u);
  const int w0 = (int)(p0 & 255u);
  #pragma unroll
  for (int tm = 0; tm < 3; ++tm)
    #pragma unroll
    for (int jr = 0; jr < 4; ++jr) {
      const int qc = cb + tm*16 + lhi*4 + jr;
      const float fb = fc3_b[qc];
      #pragma unroll
      for (int tn = 0; tn < 2; ++tn) {
        const int pix = pbx + tn*16 + l16;
        const float v = facc[tm][tn][jr] + fb + us2f(zt[swzN(pix, qc, 192)]);
        out[((size_t)(b*192 + qc)*256 + h)*256 + w0 + pix] = v;
      }
    }
}

extern "C" void kernel_launch(void* const* d_in, const int* in_sizes, int n_in,
                              void* d_out, int out_size, void* d_ws, size_t ws_size,
                              hipStream_t stream)
{
  const float* x       = (const float*)d_in[0];
  const float* ln1_g   = (const float*)d_in[1];
  const float* ln1_b   = (const float*)d_in[2];
  const float* qkv_w   = (const float*)d_in[3];
  const float* qkv_b   = (const float*)d_in[4];
  const float* bias_tb = (const float*)d_in[5];
  const float* proj_w  = (const float*)d_in[6];
  const float* proj_b  = (const float*)d_in[7];
  const float* ln2_g   = (const float*)d_in[8];
  const float* ln2_b   = (const float*)d_in[9];
  const float* fc1_w   = (const float*)d_in[10];
  const float* fc1_b   = (const float*)d_in[11];
  const float* fc2_w   = (const float*)d_in[12];
  const float* fc2_b   = (const float*)d_in[13];
  const float* fc3_w   = (const float*)d_in[14];
  const float* fc3_b   = (const float*)d_in[15];
  float* outp = (float*)d_out;

  char* ws = (char*)d_ws;
  float* meanp  = (float*)(ws);                // 524288 B
  float* rstdp  = (float*)(ws + 524288);       // 524288 B
  u16*   qkv_wT = (u16*)(ws + 1048576);        // 221184 B
  u16*   projT  = (u16*)(ws + 1269760);        // 73728 B
  u16*   fc1c   = (u16*)(ws + 1343488);        // 294912 B
  u16*   fc2c   = (u16*)(ws + 1638400);        // 294912 B
  u16*   fc3c   = (u16*)(ws + 1933312);        // 294912 B
  u16*   zbuf   = (u16*)(ws + 2228224);        // 50331648 B (total ~52.6 MB)

  hipFuncSetAttribute((const void*)k_attn, hipFuncAttributeMaxDynamicSharedMemorySize, 147712);
  hipFuncSetAttribute((const void*)k_ffn,  hipFuncAttributeMaxDynamicSharedMemorySize, 40960);

  k_ln1_stats<<<512, 256, 0, stream>>>(x, meanp, rstdp);
  k_prep<<<2304, 256, 0, stream>>>(qkv_w, proj_w, fc1_w, fc2_w, fc3_w,
                                   qkv_wT, projT, fc1c, fc2c, fc3c);
  k_attn<<<2048, 768, 147712, stream>>>(x, meanp, rstdp, ln1_g, ln1_b,
                                        qkv_wT, qkv_b, bias_tb, projT, proj_b,
                                        ln2_g, ln2_b, zbuf);
  k_ffn<<<2048, 512, 40960, stream>>>(zbuf, fc1c, fc1_b, fc2c, fc2_b,
                                      fc3c, fc3_b, outp);
}